// Round 4
// baseline (840.338 us; speedup 1.0000x reference)
//
#include <hip/hip_runtime.h>
#include <hip/hip_fp16.h>

#define G_ 512
#define B_ 64
#define I_ 32
#define H_ 64
#define NGATE 256  // 4*H

typedef _Float16 half8 __attribute__((ext_vector_type(8)));
typedef _Float16 h2 __attribute__((ext_vector_type(2)));
typedef float f32x4 __attribute__((ext_vector_type(4)));

#if __has_builtin(__builtin_amdgcn_fdot2)
#define FDOT2(a, b, c) __builtin_amdgcn_fdot2((a), (b), (c), false)
#else
#define FDOT2(a, b, c) ((c) + (float)(a)[0] * (float)(b)[0] + (float)(a)[1] * (float)(b)[1])
#endif

__device__ __forceinline__ float sigf(float x) {
  return 1.0f / (1.0f + __expf(-x));
}
__device__ __forceinline__ float tanh_fast(float x) {
  x = fminf(fmaxf(x, -15.0f), 15.0f);
  float e = __expf(2.0f * x);
  return (e - 1.0f) / (e + 1.0f);
}

// ---------------- K1: xproj[g][b][j] = input[g,b,:] . W_ih[j,:] + b_ih[j] + b_hh[j]
__global__ __launch_bounds__(256) void k_xproj(
    const float* __restrict__ input, const float* __restrict__ W_ih,
    const float* __restrict__ b_ih, const float* __restrict__ b_hh,
    _Float16* __restrict__ xproj) {
  const int g = blockIdx.x;
  const int j = threadIdx.x;
  __shared__ alignas(16) float inp[B_ * I_];
  const float* ing = input + (size_t)g * (B_ * I_);
#pragma unroll
  for (int t = 0; t < (B_ * I_) / 256; ++t) inp[t * 256 + j] = ing[t * 256 + j];
  float w[I_];
#pragma unroll
  for (int k = 0; k < I_; k += 4) {
    f32x4 v = *(const f32x4*)(W_ih + j * I_ + k);
    w[k] = v[0]; w[k + 1] = v[1]; w[k + 2] = v[2]; w[k + 3] = v[3];
  }
  const float bias = b_ih[j] + b_hh[j];
  __syncthreads();
  for (int b = 0; b < B_; ++b) {
    float a0 = bias, a1 = 0.f, a2 = 0.f, a3 = 0.f;
#pragma unroll
    for (int k = 0; k < I_; k += 4) {
      f32x4 iv = *(const f32x4*)&inp[b * I_ + k];
      a0 += iv[0] * w[k]; a1 += iv[1] * w[k + 1];
      a2 += iv[2] * w[k + 2]; a3 += iv[3] * w[k + 3];
    }
    xproj[((size_t)g * B_ + b) * NGATE + j] = (_Float16)((a0 + a1) + (a2 + a3));
  }
}

// ---------------- K2: LSTM scan, one wave per batch row (exact round-2 version).
__global__ __launch_bounds__(64) void k_scan(
    const _Float16* __restrict__ xproj, const float* __restrict__ h0,
    const float* __restrict__ c0, const float* __restrict__ W_hh,
    _Float16* __restrict__ hs) {
  const int b = blockIdx.x;
  const int j = threadIdx.x;  // 0..63
  __shared__ alignas(16) _Float16 hsh[H_];

  h2 w[4][32];
#pragma unroll
  for (int q = 0; q < 4; ++q) {
    const float* wr = W_hh + (size_t)(q * H_ + j) * H_;
#pragma unroll
    for (int k = 0; k < 32; ++k) {
      h2 t;
      t[0] = (_Float16)wr[2 * k];
      t[1] = (_Float16)wr[2 * k + 1];
      w[q][k] = t;
    }
  }
  float c = c0[b * H_ + j];
  hsh[j] = (_Float16)h0[b * H_ + j];

  const _Float16* xp = xproj + (size_t)b * NGATE;
  float xg[4], xn[4];
#pragma unroll
  for (int q = 0; q < 4; ++q) xg[q] = (float)xp[q * H_ + j];

  for (int g = 0; g < G_; ++g) {
    if (g + 1 < G_) {
      const _Float16* xq = xp + (size_t)(g + 1) * (B_ * NGATE);
#pragma unroll
      for (int q = 0; q < 4; ++q) xn[q] = (float)xq[q * H_ + j];
    }
    __syncthreads();
    const h2* hp = (const h2*)hsh;
    float a[4], a2[4];
#pragma unroll
    for (int q = 0; q < 4; ++q) { a[q] = xg[q]; a2[q] = 0.0f; }
#pragma unroll
    for (int k = 0; k < 16; ++k) {
      h2 hv = hp[k];
#pragma unroll
      for (int q = 0; q < 4; ++q) a[q] = FDOT2(hv, w[q][k], a[q]);
    }
#pragma unroll
    for (int k = 16; k < 32; ++k) {
      h2 hv = hp[k];
#pragma unroll
      for (int q = 0; q < 4; ++q) a2[q] = FDOT2(hv, w[q][k], a2[q]);
    }
#pragma unroll
    for (int q = 0; q < 4; ++q) a[q] += a2[q];

    float ig = sigf(a[0]);
    float fg = sigf(a[1]);
    float gg = tanh_fast(a[2]);
    float og = sigf(a[3]);
    c = fg * c + ig * gg;
    float hh = og * tanh_fast(c);
    _Float16 hf = (_Float16)hh;
    __syncthreads();
    hsh[j] = hf;
    hs[(size_t)b * (G_ * H_) + (size_t)g * H_ + j] = hf;
#pragma unroll
    for (int q = 0; q < 4; ++q) xg[q] = xn[q];
  }
}

// ---------------- GEMM: part[ks][m][n] = X[m, kchunk] . W[n, kchunk]  (round-2 version)
template <int N, int K, int KC, int NTILES>
__global__ __launch_bounds__(256) void k_gemm(
    const _Float16* __restrict__ X, const float* __restrict__ W,
    float* __restrict__ part) {
  const int bid = blockIdx.x;
  const int n0 = (bid % NTILES) * 64;
  const int ks = bid / NTILES;
  const int lane = threadIdx.x & 63;
  const int wave = threadIdx.x >> 6;
  const int r = lane & 15;
  const int gq = lane >> 4;
  const int ncol = n0 + wave * 16 + r;
  const float* wrow = W + (size_t)ncol * K + 8 * gq + (size_t)ks * KC;
  const _Float16* xrow = X + (size_t)r * K + 8 * gq + (size_t)ks * KC;
  f32x4 acc[4] = {};
#pragma unroll 4
  for (int k = 0; k < KC; k += 32) {
    f32x4 blo = *(const f32x4*)(wrow + k);
    f32x4 bhi = *(const f32x4*)(wrow + k + 4);
    half8 bf;
    bf[0] = (_Float16)blo[0]; bf[1] = (_Float16)blo[1];
    bf[2] = (_Float16)blo[2]; bf[3] = (_Float16)blo[3];
    bf[4] = (_Float16)bhi[0]; bf[5] = (_Float16)bhi[1];
    bf[6] = (_Float16)bhi[2]; bf[7] = (_Float16)bhi[3];
#pragma unroll
    for (int mi = 0; mi < 4; ++mi) {
      half8 af = *(const half8*)(xrow + (size_t)(mi * 16) * K + k);
      acc[mi] = __builtin_amdgcn_mfma_f32_16x16x32_f16(af, bf, acc[mi], 0, 0, 0);
    }
  }
#pragma unroll
  for (int mi = 0; mi < 4; ++mi) {
#pragma unroll
    for (int q = 0; q < 4; ++q) {
      int row = mi * 16 + gq * 4 + q;
      part[((size_t)ks * 64 + row) * N + n0 + wave * 16 + r] = acc[mi][q];
    }
  }
}

// ---------------- reduce k-split partials + bias -> f16 activations (x4 vectorized)
template <int N, int KS>
__global__ __launch_bounds__(256) void k_reduce(
    const float* __restrict__ part, const float* __restrict__ bias,
    _Float16* __restrict__ out) {
  const int idx4 = (blockIdx.x * 256 + threadIdx.x) * 4;
  const int n = idx4 % N;
  f32x4 s = *(const f32x4*)(bias + n);
#pragma unroll
  for (int ks = 0; ks < KS; ++ks) s += *(const f32x4*)(part + (size_t)ks * 64 * N + idx4);
#pragma unroll
  for (int t = 0; t < 4; ++t) out[idx4 + t] = (_Float16)s[t];
}

// ---------------- final reduce + bias + sigmoid -> fp32 output
template <int N, int KS>
__global__ __launch_bounds__(256) void k_reduce_sig(
    const float* __restrict__ part, const float* __restrict__ bias,
    float* __restrict__ out) {
  const int idx4 = (blockIdx.x * 256 + threadIdx.x) * 4;
  const int n = idx4 % N;
  f32x4 s = *(const f32x4*)(bias + n);
#pragma unroll
  for (int ks = 0; ks < KS; ++ks) s += *(const f32x4*)(part + (size_t)ks * 64 * N + idx4);
#pragma unroll
  for (int t = 0; t < 4; ++t) out[idx4 + t] = sigf(s[t]);
}

extern "C" void kernel_launch(void* const* d_in, const int* in_sizes, int n_in,
                              void* d_out, int out_size, void* d_ws, size_t ws_size,
                              hipStream_t stream) {
  const float* input = (const float*)d_in[0];
  const float* h0    = (const float*)d_in[1];
  const float* c0    = (const float*)d_in[2];
  const float* W_ih  = (const float*)d_in[3];
  const float* W_hh  = (const float*)d_in[4];
  const float* b_ih  = (const float*)d_in[5];
  const float* b_hh  = (const float*)d_in[6];
  const float* W1    = (const float*)d_in[7];
  const float* b1    = (const float*)d_in[8];
  const float* W2    = (const float*)d_in[9];
  const float* b2    = (const float*)d_in[10];
  const float* W3    = (const float*)d_in[11];
  const float* b3    = (const float*)d_in[12];
  float* out = (float*)d_out;

  uint8_t* ws = (uint8_t*)d_ws;
  float*    part  = (float*)ws;
  _Float16* xproj = (_Float16*)ws;
  _Float16* hs    = (_Float16*)(ws + 41943040);
  _Float16* x2    = (_Float16*)(ws + 46137344);
  _Float16* x3    = (_Float16*)(ws + 46792704);

  k_xproj<<<G_, 256, 0, stream>>>(input, W_ih, b_ih, b_hh, xproj);
  // PROBE (this round only): launch the scan twice. The second launch is
  // idempotent (recomputes from h0/c0, overwrites hs identically), so
  // dur_us - 587 measures the scan's true duration for attribution.
  k_scan<<<B_, 64, 0, stream>>>(xproj, h0, c0, W_hh, hs);
  k_scan<<<B_, 64, 0, stream>>>(xproj, h0, c0, W_hh, hs);
  // GEMM1: [64,32768] x W1[5120,32768]^T, ksplit=32 (KC=1024), 80 n-tiles -> 2560 blocks
  k_gemm<5120, 32768, 1024, 80><<<80 * 32, 256, 0, stream>>>(hs, W1, part);
  k_reduce<5120, 32><<<(64 * 5120) / 4 / 256, 256, 0, stream>>>(part, b1, x2);
  // GEMM2: [64,5120] x W2[2560,5120]^T, ksplit=8 (KC=640), 40 n-tiles -> 320 blocks
  k_gemm<2560, 5120, 640, 40><<<40 * 8, 256, 0, stream>>>(x2, W2, part);
  k_reduce<2560, 8><<<(64 * 2560) / 4 / 256, 256, 0, stream>>>(part, b2, x3);
  // GEMM3: [64,2560] x W3[512,2560]^T, ksplit=8 (KC=320), 8 n-tiles -> 64 blocks
  k_gemm<512, 2560, 320, 8><<<8 * 8, 256, 0, stream>>>(x3, W3, part);
  k_reduce_sig<512, 8><<<(64 * 512) / 4 / 256, 256, 0, stream>>>(part, b3, out);
}

// Round 5
// 576.026 us; speedup vs baseline: 1.4589x; 1.4589x over previous
//
#include <hip/hip_runtime.h>
#include <hip/hip_fp16.h>

#define G_ 512
#define B_ 64
#define I_ 32
#define H_ 64
#define NGATE 256  // 4*H

typedef _Float16 half8 __attribute__((ext_vector_type(8)));
typedef _Float16 h4 __attribute__((ext_vector_type(4)));
typedef _Float16 h2 __attribute__((ext_vector_type(2)));
typedef float f32x4 __attribute__((ext_vector_type(4)));

#if __has_builtin(__builtin_amdgcn_fdot2)
#define FDOT2(a, b, c) __builtin_amdgcn_fdot2((a), (b), (c), false)
#else
#define FDOT2(a, b, c) ((c) + (float)(a)[0] * (float)(b)[0] + (float)(a)[1] * (float)(b)[1])
#endif

__device__ __forceinline__ float sigf(float x) {
  return 1.0f / (1.0f + __expf(-x));
}
__device__ __forceinline__ float tanh_fast(float x) {
  x = fminf(fmaxf(x, -15.0f), 15.0f);
  float e = __expf(2.0f * x);
  return (e - 1.0f) / (e + 1.0f);
}

// ---------------- K1: xproj2[b][g][col*4+q] = input[g,b,:] . W_ih[q*64+col,:] + bias
// Thread t -> col = t>>2, gate q = t&3, so the block's 256 stores per (g,b) are
// byte-contiguous (offset == t). Scan lane j then reads all 4 gates as one b64.
__global__ __launch_bounds__(256) void k_xproj(
    const float* __restrict__ input, const float* __restrict__ W_ih,
    const float* __restrict__ b_ih, const float* __restrict__ b_hh,
    _Float16* __restrict__ xproj) {
  const int g = blockIdx.x;
  const int t = threadIdx.x;
  const int col = t >> 2;
  const int q = t & 3;
  const int row = q * H_ + col;  // gate-row in torch i,f,g,o order
  __shared__ alignas(16) float inp[B_ * I_];
  const float* ing = input + (size_t)g * (B_ * I_);
#pragma unroll
  for (int u = 0; u < (B_ * I_) / 256; ++u) inp[u * 256 + t] = ing[u * 256 + t];
  float w[I_];
#pragma unroll
  for (int k = 0; k < I_; k += 4) {
    f32x4 v = *(const f32x4*)(W_ih + (size_t)row * I_ + k);
    w[k] = v[0]; w[k + 1] = v[1]; w[k + 2] = v[2]; w[k + 3] = v[3];
  }
  const float bias = b_ih[row] + b_hh[row];
  __syncthreads();
  for (int b = 0; b < B_; ++b) {
    float a0 = bias, a1 = 0.f, a2 = 0.f, a3 = 0.f;
#pragma unroll
    for (int k = 0; k < I_; k += 4) {
      f32x4 iv = *(const f32x4*)&inp[b * I_ + k];
      a0 += iv[0] * w[k]; a1 += iv[1] * w[k + 1];
      a2 += iv[2] * w[k + 2]; a3 += iv[3] * w[k + 3];
    }
    xproj[((size_t)b * G_ + g) * NGATE + t] = (_Float16)((a0 + a1) + (a2 + a3));
  }
}

// ---------------- K2: LSTM scan, one wave per batch row, BARRIER-FREE.
// No __syncthreads in the loop (it emits s_waitcnt vmcnt(0), draining the
// prefetch => 900-cyc HBM latency exposed per step; that was the 253 us).
// Single-wave LDS recurrence is in-order per wave (R3 passed correctness).
// xproj ring: depth-8 register prefetch of one coalesced b64 per lane per step.
__global__ __launch_bounds__(64) void k_scan(
    const _Float16* __restrict__ xproj, const float* __restrict__ h0,
    const float* __restrict__ c0, const float* __restrict__ W_hh,
    _Float16* __restrict__ hs) {
  const int b = blockIdx.x;
  const int j = threadIdx.x;  // 0..63
  __shared__ alignas(16) _Float16 hsh[H_];

  h2 w[4][32];
#pragma unroll
  for (int q = 0; q < 4; ++q) {
    const f32x4* wr = (const f32x4*)(W_hh + (size_t)(q * H_ + j) * H_);
#pragma unroll
    for (int kk = 0; kk < 16; ++kk) {
      f32x4 v = wr[kk];
      h2 t0, t1;
      t0[0] = (_Float16)v[0]; t0[1] = (_Float16)v[1];
      t1[0] = (_Float16)v[2]; t1[1] = (_Float16)v[3];
      w[q][2 * kk] = t0;
      w[q][2 * kk + 1] = t1;
    }
  }
  float c = c0[b * H_ + j];
  hsh[j] = (_Float16)h0[b * H_ + j];

  // lane j's per-step record: xproj[b][g][j*4 .. j*4+3] -> h4 at index g*64 + j
  const h4* xrow = (const h4*)(xproj + (size_t)b * G_ * NGATE) + j;
  h4 p[8];
#pragma unroll
  for (int d = 0; d < 8; ++d) p[d] = xrow[(size_t)d * 64];

  _Float16* hrow = hs + (size_t)b * (G_ * H_) + j;

  for (int g0 = 0; g0 < G_; g0 += 8) {
#pragma unroll
    for (int d = 0; d < 8; ++d) {
      const int g = g0 + d;
      float a[4], a2[4];
#pragma unroll
      for (int q = 0; q < 4; ++q) { a[q] = (float)p[d][q]; a2[q] = 0.0f; }
      const f32x4* hp4 = (const f32x4*)hsh;
#pragma unroll
      for (int k4 = 0; k4 < 4; ++k4) {
        f32x4 hv4 = hp4[k4];
#pragma unroll
        for (int t = 0; t < 4; ++t) {
          h2 hv = __builtin_bit_cast(h2, hv4[t]);
#pragma unroll
          for (int q = 0; q < 4; ++q) a[q] = FDOT2(hv, w[q][k4 * 4 + t], a[q]);
        }
      }
#pragma unroll
      for (int k4 = 4; k4 < 8; ++k4) {
        f32x4 hv4 = hp4[k4];
#pragma unroll
        for (int t = 0; t < 4; ++t) {
          h2 hv = __builtin_bit_cast(h2, hv4[t]);
#pragma unroll
          for (int q = 0; q < 4; ++q) a2[q] = FDOT2(hv, w[q][k4 * 4 + t], a2[q]);
        }
      }
#pragma unroll
      for (int q = 0; q < 4; ++q) a[q] += a2[q];

      float ig = sigf(a[0]);
      float fg = sigf(a[1]);
      float gg = tanh_fast(a[2]);
      float og = sigf(a[3]);
      c = fg * c + ig * gg;
      float hh = og * tanh_fast(c);
      _Float16 hf = (_Float16)hh;
      hsh[j] = hf;              // in-order LDS within the wave orders this vs next reads
      hrow[(size_t)g * H_] = hf;
      // refill slot d for step g+8 (issued ~8 steps = ~3600 cyc before use)
      if (g + 8 < G_) p[d] = xrow[(size_t)(g + 8) * 64];
    }
  }
}

// ---------------- GEMM: part[ks][m][n] = X[m, kchunk] . W[n, kchunk]  (round-2 version)
template <int N, int K, int KC, int NTILES>
__global__ __launch_bounds__(256) void k_gemm(
    const _Float16* __restrict__ X, const float* __restrict__ W,
    float* __restrict__ part) {
  const int bid = blockIdx.x;
  const int n0 = (bid % NTILES) * 64;
  const int ks = bid / NTILES;
  const int lane = threadIdx.x & 63;
  const int wave = threadIdx.x >> 6;
  const int r = lane & 15;
  const int gq = lane >> 4;
  const int ncol = n0 + wave * 16 + r;
  const float* wrow = W + (size_t)ncol * K + 8 * gq + (size_t)ks * KC;
  const _Float16* xrow = X + (size_t)r * K + 8 * gq + (size_t)ks * KC;
  f32x4 acc[4] = {};
#pragma unroll 4
  for (int k = 0; k < KC; k += 32) {
    f32x4 blo = *(const f32x4*)(wrow + k);
    f32x4 bhi = *(const f32x4*)(wrow + k + 4);
    half8 bf;
    bf[0] = (_Float16)blo[0]; bf[1] = (_Float16)blo[1];
    bf[2] = (_Float16)blo[2]; bf[3] = (_Float16)blo[3];
    bf[4] = (_Float16)bhi[0]; bf[5] = (_Float16)bhi[1];
    bf[6] = (_Float16)bhi[2]; bf[7] = (_Float16)bhi[3];
#pragma unroll
    for (int mi = 0; mi < 4; ++mi) {
      half8 af = *(const half8*)(xrow + (size_t)(mi * 16) * K + k);
      acc[mi] = __builtin_amdgcn_mfma_f32_16x16x32_f16(af, bf, acc[mi], 0, 0, 0);
    }
  }
#pragma unroll
  for (int mi = 0; mi < 4; ++mi) {
#pragma unroll
    for (int q = 0; q < 4; ++q) {
      int row = mi * 16 + gq * 4 + q;
      part[((size_t)ks * 64 + row) * N + n0 + wave * 16 + r] = acc[mi][q];
    }
  }
}

// ---------------- reduce k-split partials + bias -> f16 activations (x4 vectorized)
template <int N, int KS>
__global__ __launch_bounds__(256) void k_reduce(
    const float* __restrict__ part, const float* __restrict__ bias,
    _Float16* __restrict__ out) {
  const int idx4 = (blockIdx.x * 256 + threadIdx.x) * 4;
  const int n = idx4 % N;
  f32x4 s = *(const f32x4*)(bias + n);
#pragma unroll
  for (int ks = 0; ks < KS; ++ks) s += *(const f32x4*)(part + (size_t)ks * 64 * N + idx4);
#pragma unroll
  for (int t = 0; t < 4; ++t) out[idx4 + t] = (_Float16)s[t];
}

// ---------------- final reduce + bias + sigmoid -> fp32 output
template <int N, int KS>
__global__ __launch_bounds__(256) void k_reduce_sig(
    const float* __restrict__ part, const float* __restrict__ bias,
    float* __restrict__ out) {
  const int idx4 = (blockIdx.x * 256 + threadIdx.x) * 4;
  const int n = idx4 % N;
  f32x4 s = *(const f32x4*)(bias + n);
#pragma unroll
  for (int ks = 0; ks < KS; ++ks) s += *(const f32x4*)(part + (size_t)ks * 64 * N + idx4);
#pragma unroll
  for (int t = 0; t < 4; ++t) out[idx4 + t] = sigf(s[t]);
}

extern "C" void kernel_launch(void* const* d_in, const int* in_sizes, int n_in,
                              void* d_out, int out_size, void* d_ws, size_t ws_size,
                              hipStream_t stream) {
  const float* input = (const float*)d_in[0];
  const float* h0    = (const float*)d_in[1];
  const float* c0    = (const float*)d_in[2];
  const float* W_ih  = (const float*)d_in[3];
  const float* W_hh  = (const float*)d_in[4];
  const float* b_ih  = (const float*)d_in[5];
  const float* b_hh  = (const float*)d_in[6];
  const float* W1    = (const float*)d_in[7];
  const float* b1    = (const float*)d_in[8];
  const float* W2    = (const float*)d_in[9];
  const float* b2    = (const float*)d_in[10];
  const float* W3    = (const float*)d_in[11];
  const float* b3    = (const float*)d_in[12];
  float* out = (float*)d_out;

  uint8_t* ws = (uint8_t*)d_ws;
  float*    part  = (float*)ws;
  _Float16* xproj = (_Float16*)ws;   // [b][g][256], 16.8 MB, dead before GEMM1
  _Float16* hs    = (_Float16*)(ws + 41943040);
  _Float16* x2    = (_Float16*)(ws + 46137344);
  _Float16* x3    = (_Float16*)(ws + 46792704);

  k_xproj<<<G_, 256, 0, stream>>>(input, W_ih, b_ih, b_hh, xproj);
  k_scan<<<B_, 64, 0, stream>>>(xproj, h0, c0, W_hh, hs);
  // GEMM1: [64,32768] x W1[5120,32768]^T, ksplit=32 (KC=1024), 80 n-tiles -> 2560 blocks
  k_gemm<5120, 32768, 1024, 80><<<80 * 32, 256, 0, stream>>>(hs, W1, part);
  k_reduce<5120, 32><<<(64 * 5120) / 4 / 256, 256, 0, stream>>>(part, b1, x2);
  // GEMM2: [64,5120] x W2[2560,5120]^T, ksplit=8 (KC=640), 40 n-tiles -> 320 blocks
  k_gemm<2560, 5120, 640, 40><<<40 * 8, 256, 0, stream>>>(x2, W2, part);
  k_reduce<2560, 8><<<(64 * 2560) / 4 / 256, 256, 0, stream>>>(part, b2, x3);
  // GEMM3: [64,2560] x W3[512,2560]^T, ksplit=8 (KC=320), 8 n-tiles -> 64 blocks
  k_gemm<512, 2560, 320, 8><<<8 * 8, 256, 0, stream>>>(x3, W3, part);
  k_reduce_sig<512, 8><<<(64 * 512) / 4 / 256, 256, 0, stream>>>(part, b3, out);
}

// Round 6
// 531.530 us; speedup vs baseline: 1.5810x; 1.0837x over previous
//
#include <hip/hip_runtime.h>
#include <hip/hip_fp16.h>

#define G_ 512
#define B_ 64
#define I_ 32
#define H_ 64
#define NGATE 256  // 4*H

typedef _Float16 half8 __attribute__((ext_vector_type(8)));
typedef _Float16 h4 __attribute__((ext_vector_type(4)));
typedef _Float16 h2 __attribute__((ext_vector_type(2)));
typedef float f32x4 __attribute__((ext_vector_type(4)));

#if __has_builtin(__builtin_amdgcn_fdot2)
#define FDOT2(a, b, c) __builtin_amdgcn_fdot2((a), (b), (c), false)
#else
#define FDOT2(a, b, c) ((c) + (float)(a)[0] * (float)(b)[0] + (float)(a)[1] * (float)(b)[1])
#endif

__device__ __forceinline__ float sigf(float x) {
  return 1.0f / (1.0f + __expf(-x));
}
__device__ __forceinline__ float tanh_fast(float x) {
  x = fminf(fmaxf(x, -15.0f), 15.0f);
  float e = __expf(2.0f * x);
  return (e - 1.0f) / (e + 1.0f);
}

// ---------------- K1: xproj[b][g][col*4+q]  (coalesced 8B-per-lane scan reads)
__global__ __launch_bounds__(256) void k_xproj(
    const float* __restrict__ input, const float* __restrict__ W_ih,
    const float* __restrict__ b_ih, const float* __restrict__ b_hh,
    _Float16* __restrict__ xproj) {
  const int g = blockIdx.x;
  const int t = threadIdx.x;
  const int col = t >> 2;
  const int q = t & 3;
  const int row = q * H_ + col;  // gate-row in torch i,f,g,o order
  __shared__ alignas(16) float inp[B_ * I_];
  const float* ing = input + (size_t)g * (B_ * I_);
#pragma unroll
  for (int u = 0; u < (B_ * I_) / 256; ++u) inp[u * 256 + t] = ing[u * 256 + t];
  float w[I_];
#pragma unroll
  for (int k = 0; k < I_; k += 4) {
    f32x4 v = *(const f32x4*)(W_ih + (size_t)row * I_ + k);
    w[k] = v[0]; w[k + 1] = v[1]; w[k + 2] = v[2]; w[k + 3] = v[3];
  }
  const float bias = b_ih[row] + b_hh[row];
  __syncthreads();
  for (int b = 0; b < B_; ++b) {
    float a0 = bias, a1 = 0.f, a2 = 0.f, a3 = 0.f;
#pragma unroll
    for (int k = 0; k < I_; k += 4) {
      f32x4 iv = *(const f32x4*)&inp[b * I_ + k];
      a0 += iv[0] * w[k]; a1 += iv[1] * w[k + 1];
      a2 += iv[2] * w[k + 2]; a3 += iv[3] * w[k + 3];
    }
    xproj[((size_t)b * G_ + g) * NGATE + t] = (_Float16)((a0 + a1) + (a2 + a3));
  }
}

// ---------------- K2: LSTM scan (round-5 version, barrier-free, depth-8 ring)
__global__ __launch_bounds__(64) void k_scan(
    const _Float16* __restrict__ xproj, const float* __restrict__ h0,
    const float* __restrict__ c0, const float* __restrict__ W_hh,
    _Float16* __restrict__ hs) {
  const int b = blockIdx.x;
  const int j = threadIdx.x;  // 0..63
  __shared__ alignas(16) _Float16 hsh[H_];

  h2 w[4][32];
#pragma unroll
  for (int q = 0; q < 4; ++q) {
    const f32x4* wr = (const f32x4*)(W_hh + (size_t)(q * H_ + j) * H_);
#pragma unroll
    for (int kk = 0; kk < 16; ++kk) {
      f32x4 v = wr[kk];
      h2 t0, t1;
      t0[0] = (_Float16)v[0]; t0[1] = (_Float16)v[1];
      t1[0] = (_Float16)v[2]; t1[1] = (_Float16)v[3];
      w[q][2 * kk] = t0;
      w[q][2 * kk + 1] = t1;
    }
  }
  float c = c0[b * H_ + j];
  hsh[j] = (_Float16)h0[b * H_ + j];

  const h4* xrow = (const h4*)(xproj + (size_t)b * G_ * NGATE) + j;
  h4 p[8];
#pragma unroll
  for (int d = 0; d < 8; ++d) p[d] = xrow[(size_t)d * 64];

  _Float16* hrow = hs + (size_t)b * (G_ * H_) + j;

  for (int g0 = 0; g0 < G_; g0 += 8) {
#pragma unroll
    for (int d = 0; d < 8; ++d) {
      const int g = g0 + d;
      float a[4], a2[4];
#pragma unroll
      for (int q = 0; q < 4; ++q) { a[q] = (float)p[d][q]; a2[q] = 0.0f; }
      const f32x4* hp4 = (const f32x4*)hsh;
#pragma unroll
      for (int k4 = 0; k4 < 4; ++k4) {
        f32x4 hv4 = hp4[k4];
#pragma unroll
        for (int t = 0; t < 4; ++t) {
          h2 hv = __builtin_bit_cast(h2, hv4[t]);
#pragma unroll
          for (int q = 0; q < 4; ++q) a[q] = FDOT2(hv, w[q][k4 * 4 + t], a[q]);
        }
      }
#pragma unroll
      for (int k4 = 4; k4 < 8; ++k4) {
        f32x4 hv4 = hp4[k4];
#pragma unroll
        for (int t = 0; t < 4; ++t) {
          h2 hv = __builtin_bit_cast(h2, hv4[t]);
#pragma unroll
          for (int q = 0; q < 4; ++q) a2[q] = FDOT2(hv, w[q][k4 * 4 + t], a2[q]);
        }
      }
#pragma unroll
      for (int q = 0; q < 4; ++q) a[q] += a2[q];

      float ig = sigf(a[0]);
      float fg = sigf(a[1]);
      float gg = tanh_fast(a[2]);
      float og = sigf(a[3]);
      c = fg * c + ig * gg;
      float hh = og * tanh_fast(c);
      _Float16 hf = (_Float16)hh;
      hsh[j] = hf;
      hrow[(size_t)g * H_] = hf;
      if (g + 8 < G_) p[d] = xrow[(size_t)(g + 8) * 64];
    }
  }
}

// ---------------- LDS-staged GEMM: part[ks][m][n] = X[m,kchunk] . W[n,kchunk]
// W staged to LDS in 512-B-contiguous-per-row wave instructions (DRAM-friendly),
// converted f32->f16 in flight, XOR-swizzled tile (G4: byte ^= (row&7)<<4) so
// the MFMA-phase ds_read_b128 (16 lanes at 256-B row stride) is conflict-free.
// Fragment k-order identical to the proven flat kernel.
template <int N, int K, int KC, int NTILES>
__global__ __launch_bounds__(256) void k_gemm_lds(
    const _Float16* __restrict__ X, const float* __restrict__ W,
    float* __restrict__ part) {
  constexpr int KW = 128;                 // k-floats per stage
  static_assert(KC % KW == 0, "stage divisibility");
  __shared__ alignas(16) _Float16 wl[64 * KW];  // 16 KB
  const int bid = blockIdx.x;
  const int n0 = (bid % NTILES) * 64;
  const int ks = bid / NTILES;
  const int kbeg = ks * KC;
  const int lane = threadIdx.x & 63;
  const int wave = threadIdx.x >> 6;
  const int r = lane & 15;
  const int gq = lane >> 4;
  const int scol = (lane & 15) * 8;       // float col within stage (8 floats/lane)
  const int rsub = lane >> 4;             // 0..3: row-within-quad for staging

  const _Float16* xrow = X + (size_t)r * K + kbeg + 8 * gq;
  f32x4 acc[4] = {};

  for (int st = 0; st < KC / KW; ++st) {
    const int kst = kbeg + st * KW;
    // ---- stage 64x128 f32 -> f16 LDS (per wave: 16 rows, 512 B contiguous each)
#pragma unroll
    for (int it = 0; it < 4; ++it) {
      const int rr = wave * 16 + it * 4 + rsub;
      const float* src = W + (size_t)(n0 + rr) * K + kst + scol;
      f32x4 v0 = *(const f32x4*)src;
      f32x4 v1 = *(const f32x4*)(src + 4);
      half8 h;
      h[0] = (_Float16)v0[0]; h[1] = (_Float16)v0[1];
      h[2] = (_Float16)v0[2]; h[3] = (_Float16)v0[3];
      h[4] = (_Float16)v1[0]; h[5] = (_Float16)v1[1];
      h[6] = (_Float16)v1[2]; h[7] = (_Float16)v1[3];
      int byte = rr * (KW * 2) + (lane & 15) * 16;
      byte ^= (rr & 7) << 4;
      *(half8*)((char*)wl + byte) = h;
    }
    __syncthreads();
    // ---- MFMA phase: 4 k-iters of 32
#pragma unroll
    for (int k32 = 0; k32 < KW; k32 += 32) {
      int rbyte = (wave * 16 + r) * (KW * 2) + (k32 + 8 * gq) * 2;
      rbyte ^= (r & 7) << 4;
      half8 bf = *(const half8*)((const char*)wl + rbyte);
      const _Float16* xp = xrow + st * KW + k32;
#pragma unroll
      for (int mi = 0; mi < 4; ++mi) {
        half8 af = *(const half8*)(xp + (size_t)(mi * 16) * K);
        acc[mi] = __builtin_amdgcn_mfma_f32_16x16x32_f16(af, bf, acc[mi], 0, 0, 0);
      }
    }
    __syncthreads();
  }
#pragma unroll
  for (int mi = 0; mi < 4; ++mi) {
#pragma unroll
    for (int q = 0; q < 4; ++q) {
      int row = mi * 16 + gq * 4 + q;
      part[((size_t)ks * 64 + row) * N + n0 + wave * 16 + r] = acc[mi][q];
    }
  }
}

// ---------------- reduce k-split partials + bias -> f16 activations (x4 vectorized)
template <int N, int KS>
__global__ __launch_bounds__(256) void k_reduce(
    const float* __restrict__ part, const float* __restrict__ bias,
    _Float16* __restrict__ out) {
  const int idx4 = (blockIdx.x * 256 + threadIdx.x) * 4;
  const int n = idx4 % N;
  f32x4 s = *(const f32x4*)(bias + n);
#pragma unroll
  for (int ks = 0; ks < KS; ++ks) s += *(const f32x4*)(part + (size_t)ks * 64 * N + idx4);
#pragma unroll
  for (int t = 0; t < 4; ++t) out[idx4 + t] = (_Float16)s[t];
}

// ---------------- final reduce + bias + sigmoid -> fp32 output
template <int N, int KS>
__global__ __launch_bounds__(256) void k_reduce_sig(
    const float* __restrict__ part, const float* __restrict__ bias,
    float* __restrict__ out) {
  const int idx4 = (blockIdx.x * 256 + threadIdx.x) * 4;
  const int n = idx4 % N;
  f32x4 s = *(const f32x4*)(bias + n);
#pragma unroll
  for (int ks = 0; ks < KS; ++ks) s += *(const f32x4*)(part + (size_t)ks * 64 * N + idx4);
#pragma unroll
  for (int t = 0; t < 4; ++t) out[idx4 + t] = sigf(s[t]);
}

extern "C" void kernel_launch(void* const* d_in, const int* in_sizes, int n_in,
                              void* d_out, int out_size, void* d_ws, size_t ws_size,
                              hipStream_t stream) {
  const float* input = (const float*)d_in[0];
  const float* h0    = (const float*)d_in[1];
  const float* c0    = (const float*)d_in[2];
  const float* W_ih  = (const float*)d_in[3];
  const float* W_hh  = (const float*)d_in[4];
  const float* b_ih  = (const float*)d_in[5];
  const float* b_hh  = (const float*)d_in[6];
  const float* W1    = (const float*)d_in[7];
  const float* b1    = (const float*)d_in[8];
  const float* W2    = (const float*)d_in[9];
  const float* b2    = (const float*)d_in[10];
  const float* W3    = (const float*)d_in[11];
  const float* b3    = (const float*)d_in[12];
  float* out = (float*)d_out;

  uint8_t* ws = (uint8_t*)d_ws;
  float*    part  = (float*)ws;
  _Float16* xproj = (_Float16*)ws;   // [b][g][256], 16.8 MB, dead before GEMM1
  _Float16* hs    = (_Float16*)(ws + 41943040);
  _Float16* x2    = (_Float16*)(ws + 46137344);
  _Float16* x3    = (_Float16*)(ws + 46792704);

  k_xproj<<<G_, 256, 0, stream>>>(input, W_ih, b_ih, b_hh, xproj);
  k_scan<<<B_, 64, 0, stream>>>(xproj, h0, c0, W_hh, hs);
  // GEMM1: [64,32768] x W1[5120,32768]^T, ksplit=32 (KC=1024), 80 n-tiles
  k_gemm_lds<5120, 32768, 1024, 80><<<80 * 32, 256, 0, stream>>>(hs, W1, part);
  k_reduce<5120, 32><<<(64 * 5120) / 4 / 256, 256, 0, stream>>>(part, b1, x2);
  // GEMM2: [64,5120] x W2[2560,5120]^T, ksplit=8 (KC=640), 40 n-tiles
  k_gemm_lds<2560, 5120, 640, 40><<<40 * 8, 256, 0, stream>>>(x2, W2, part);
  k_reduce<2560, 8><<<(64 * 2560) / 4 / 256, 256, 0, stream>>>(part, b2, x3);
  // GEMM3: [64,2560] x W3[512,2560]^T, ksplit=10 (KC=256), 8 n-tiles
  k_gemm_lds<512, 2560, 256, 8><<<8 * 10, 256, 0, stream>>>(x3, W3, part);
  k_reduce_sig<512, 10><<<(64 * 512) / 4 / 256, 256, 0, stream>>>(part, b3, out);
}